// Round 12
// baseline (424.597 us; speedup 1.0000x reference)
//
#include <hip/hip_runtime.h>
#include <hip/hip_fp16.h>

// ---------------------------------------------------------------------------
// GCN forward. CSR build = 3-level radix/counting sort with all global writes
// coalesced. Aggregation = bucket-phased gather (round-10 structure) with
// node-pair MLP: each lane group walks TWO dest nodes through the SAME bucket
// phase -> 4 gathers in flight/lane, phase footprint still one 1.6 MB slice
// (round-11: cross-phase dual-cursor broke L2 locality, FETCH +51%).
// ---------------------------------------------------------------------------

#define NBKT 8
#define CAP  262144   // per-partition staging cap (E/8 = 200k avg)
#define SUBD 128      // dests per sub-bin
#define CAP2 4096     // per-sub-bin cap (mean 2048, sigma ~45)

__global__ __launch_bounds__(256) void zero_i32_kernel(int* __restrict__ p, int n) {
    int i = blockIdx.x * blockDim.x + threadIdx.x;
    if (i < n) p[i] = 0;
}

// Pass 1: bin edges by dest partition. LDS count -> block bulk-reserve ->
// append packed (r<<14 | c-lo) to stag1[part]. Append-contiguous writes.
__global__ __launch_bounds__(256) void bin_kernel(const int* __restrict__ row,
                                                  const int* __restrict__ col,
                                                  int* __restrict__ pcnt,
                                                  unsigned* __restrict__ stag,
                                                  int E, int span) {
    __shared__ int scnt[NBKT];
    __shared__ int gbase[NBKT];
    const int tid = threadIdx.x;
    for (int base = blockIdx.x * 1024; base < E; base += gridDim.x * 1024) {
        if (tid < NBKT) scnt[tid] = 0;
        __syncthreads();
        int e0 = base + tid * 4;
        unsigned pk[4]; int pt[4], lp[4];
        if (e0 + 4 <= E) {
            int4 r4 = *(const int4*)(row + e0);
            int4 c4 = *(const int4*)(col + e0);
            int rr[4] = {r4.x, r4.y, r4.z, r4.w};
            int cc[4] = {c4.x, c4.y, c4.z, c4.w};
#pragma unroll
            for (int u = 0; u < 4; ++u) {
                int p = cc[u] / span;
                pt[u] = p;
                pk[u] = ((unsigned)rr[u] << 14) | (unsigned)(cc[u] - p * span);
                lp[u] = atomicAdd(&scnt[p], 1);
            }
        } else {
#pragma unroll
            for (int u = 0; u < 4; ++u) {
                int e = e0 + u;
                if (e < E) {
                    int r = row[e], c = col[e];
                    int p = c / span;
                    pt[u] = p;
                    pk[u] = ((unsigned)r << 14) | (unsigned)(c - p * span);
                    lp[u] = atomicAdd(&scnt[p], 1);
                } else pt[u] = -1;
            }
        }
        __syncthreads();
        if (tid < NBKT) gbase[tid] = atomicAdd(&pcnt[tid], scnt[tid]);
        __syncthreads();
#pragma unroll
        for (int u = 0; u < 4; ++u) {
            if (e0 + u < E) {
                stag[(size_t)pt[u] * CAP + (unsigned)(gbase[pt[u]] + lp[u])] = pk[u];
            }
        }
        __syncthreads();
    }
}

// Pass 2: within partition, bin by sub-bin (c_local>>7). Repack (r<<7 | c&127).
__global__ __launch_bounds__(256) void bin2_kernel(const unsigned* __restrict__ stag1,
                                                   const int* __restrict__ pcnt,
                                                   int* __restrict__ pcnt2,
                                                   unsigned* __restrict__ stag2,
                                                   int nsb) {
    __shared__ int scnt[128];
    __shared__ int gbase[128];
    const int part = blockIdx.x & 7;
    const int n = min(pcnt[part], CAP);
    const unsigned* s = stag1 + (size_t)part * CAP;
    const int t0 = (blockIdx.x >> 3) * 4096;
    if (t0 >= n) return;
    const int tn = min(4096, n - t0);
    const int tid = threadIdx.x;

    for (int i = tid; i < nsb; i += 256) scnt[i] = 0;
    __syncthreads();
    for (int i = tid; i < tn; i += 256) {
        unsigned v = s[t0 + i];
        atomicAdd(&scnt[(v & 0x3FFF) >> 7], 1);
    }
    __syncthreads();
    for (int i = tid; i < nsb; i += 256) {
        gbase[i] = atomicAdd(&pcnt2[part * nsb + i], scnt[i]);
        scnt[i] = 0;
    }
    __syncthreads();
    for (int i = tid; i < tn; i += 256) {
        unsigned v = s[t0 + i];
        int cl = v & 0x3FFF;
        int sb = cl >> 7;
        int lp = atomicAdd(&scnt[sb], 1);
        int pos = min(gbase[sb] + lp, CAP2 - 1);  // clamp (never triggers)
        stag2[(size_t)(part * nsb + sb) * CAP2 + pos] = ((v >> 14) << 7) | (unsigned)(cl & 127);
    }
}

// exclusive scan of src[n] -> dst[n], n <= 1024, single block
__global__ __launch_bounds__(1024) void scan_small_kernel(const int* __restrict__ src,
                                                          int* __restrict__ dst, int n) {
    __shared__ int s[1024];
    int tid = threadIdx.x;
    int v = (tid < n) ? src[tid] : 0;
    s[tid] = v;
    __syncthreads();
    for (int off = 1; off < 1024; off <<= 1) {
        int t = (tid >= off) ? s[tid - off] : 0;
        __syncthreads();
        s[tid] += t;
        __syncthreads();
    }
    if (tid < n) dst[tid] = s[tid] - v;
}

// Pass 3: one workgroup per sub-bin. LDS counting sort over 1024 keys
// (c_local7 * 8 + src_bucket); writes offs2 segment + sorted eidx coalesced.
__global__ __launch_bounds__(256) void sort_sub_kernel(const unsigned* __restrict__ stag2,
                                                       const int* __restrict__ pcnt2,
                                                       const int* __restrict__ sbase,
                                                       int* __restrict__ offs2,
                                                       int* __restrict__ eidx,
                                                       int span, int nsb, int E) {
    __shared__ int cnt[1024];
    __shared__ int tsum[256];
    __shared__ int lout[CAP2];
    const int part = blockIdx.x & 7;
    const int sb   = blockIdx.x >> 3;
    if (sb >= nsb) return;
    const int sbg  = part * nsb + sb;
    const int n    = min(pcnt2[sbg], CAP2);
    const unsigned* s = stag2 + (size_t)sbg * CAP2;
    const int base = sbase[sbg];
    const int c0   = part * span + sb * SUBD;
    const int dd   = min(SUBD, span - sb * SUBD);
    const int tid  = threadIdx.x;

    for (int i = tid; i < 1024; i += 256) cnt[i] = 0;
    __syncthreads();
    for (int i = tid; i < n; i += 256) {
        unsigned v = s[i];
        int r = v >> 7;
        atomicAdd(&cnt[((v & 127) << 3) | (r / span)], 1);
    }
    __syncthreads();
    int a0 = cnt[tid * 4], a1 = cnt[tid * 4 + 1], a2 = cnt[tid * 4 + 2], a3 = cnt[tid * 4 + 3];
    int tot = a0 + a1 + a2 + a3;
    tsum[tid] = tot;
    __syncthreads();
    for (int off = 1; off < 256; off <<= 1) {
        int t = (tid >= off) ? tsum[tid - off] : 0;
        __syncthreads();
        tsum[tid] += t;
        __syncthreads();
    }
    int pre = tsum[tid] - tot;
    cnt[tid * 4]     = pre;
    cnt[tid * 4 + 1] = pre + a0;
    cnt[tid * 4 + 2] = pre + a0 + a1;
    cnt[tid * 4 + 3] = pre + a0 + a1 + a2;
    __syncthreads();
    for (int k = tid; k < dd * 8; k += 256) offs2[(size_t)c0 * 8 + k] = base + cnt[k];
    if (part == NBKT - 1 && sb == nsb - 1 && tid == 0) offs2[(size_t)(c0 + dd) * 8] = base + n;
    __syncthreads();
    for (int i = tid; i < n; i += 256) {
        unsigned v = s[i];
        int r = v >> 7;
        int p = atomicAdd(&cnt[((v & 127) << 3) | (r / span)], 1);
        lout[p] = r;
    }
    __syncthreads();
    for (int i = tid; i < n; i += 256) eidx[base + i] = lout[i];
}

__global__ __launch_bounds__(256) void dinv2_kernel(const int* __restrict__ offs2,
                                                    float* __restrict__ dinv, int N) {
    int i = blockIdx.x * blockDim.x + threadIdx.x;
    if (i < N) {
        int deg = offs2[i * NBKT + NBKT] - offs2[i * NBKT];
        dinv[i] = rsqrtf((float)deg + 1.0f);  // +1 self-loop
    }
}

// H(fp16) = ((RELU? relu(in) : in) @ W) * dinv[row].  W is [F_IN,F_OUT] rowmaj.
template <int F_IN, int F_OUT, bool RELU>
__global__ __launch_bounds__(256, 4) void gemm_tile_kernel(const float* __restrict__ in,
                                                           const float* __restrict__ W,
                                                           const float* __restrict__ dinv,
                                                           ushort* __restrict__ outh, int N) {
    constexpr int TC   = F_OUT / 4;
    constexpr int TR   = 256 / TC;
    constexpr int ROWS = TR * 4;
    constexpr int NKB  = F_IN / 64;
    __shared__ float sIn[ROWS][68];
    __shared__ float sW[64][F_OUT];

    const int tc = threadIdx.x % TC;
    const int tr = threadIdx.x / TC;
    const int r0 = blockIdx.x * ROWS;

    float acc[4][4] = {};

#pragma unroll
    for (int kb = 0; kb < NKB; ++kb) {
        if (kb) __syncthreads();
        for (int idx = threadIdx.x; idx < ROWS * 16; idx += 256) {
            int rr = idx / 16, c4 = (idx % 16) * 4;
            int gr = min(r0 + rr, N - 1);
            float4 v = *(const float4*)&in[(size_t)gr * F_IN + kb * 64 + c4];
            if (RELU) {
                v.x = fmaxf(v.x, 0.f); v.y = fmaxf(v.y, 0.f);
                v.z = fmaxf(v.z, 0.f); v.w = fmaxf(v.w, 0.f);
            }
            *(float4*)&sIn[rr][c4] = v;
        }
        for (int idx = threadIdx.x; idx < 64 * F_OUT / 4; idx += 256) {
            int kr = idx / (F_OUT / 4), c4 = (idx % (F_OUT / 4)) * 4;
            *(float4*)&sW[kr][c4] = *(const float4*)&W[(size_t)(kb * 64 + kr) * F_OUT + c4];
        }
        __syncthreads();
#pragma unroll 2
        for (int kk = 0; kk < 64; kk += 4) {
            float4 iv[4], wv[4];
#pragma unroll
            for (int i = 0; i < 4; ++i) iv[i] = *(const float4*)&sIn[tr * 4 + i][kk];
#pragma unroll
            for (int q = 0; q < 4; ++q) wv[q] = *(const float4*)&sW[kk + q][tc * 4];
#pragma unroll
            for (int i = 0; i < 4; ++i) {
                const float ik[4] = {iv[i].x, iv[i].y, iv[i].z, iv[i].w};
#pragma unroll
                for (int q = 0; q < 4; ++q) {
                    acc[i][0] = fmaf(ik[q], wv[q].x, acc[i][0]);
                    acc[i][1] = fmaf(ik[q], wv[q].y, acc[i][1]);
                    acc[i][2] = fmaf(ik[q], wv[q].z, acc[i][2]);
                    acc[i][3] = fmaf(ik[q], wv[q].w, acc[i][3]);
                }
            }
        }
    }
#pragma unroll
    for (int i = 0; i < 4; ++i) {
        int r = r0 + tr * 4 + i;
        if (r < N) {
            float d = dinv[r];
            ushort4 v;
            v.x = __half_as_ushort(__float2half(acc[i][0] * d));
            v.y = __half_as_ushort(__float2half(acc[i][1] * d));
            v.z = __half_as_ushort(__float2half(acc[i][2] * d));
            v.w = __half_as_ushort(__float2half(acc[i][3] * d));
            *(ushort4*)&outh[(size_t)r * F_OUT + tc * 4] = v;
        }
    }
}

__device__ inline void h8acc(float* acc, uint4 u) {
    const __half2* p = (const __half2*)&u;
#pragma unroll
    for (int i = 0; i < 4; ++i) {
        float2 f = __half22float2(p[i]);
        acc[2 * i]     += f.x;
        acc[2 * i + 1] += f.y;
    }
}

// out[c, jw*8..+7] = b + dinv[c]*( sum_{neighbors} H16[r] + H16[c] )
// Node-pair MLP: lane group walks nodes (2p, 2p+1) through bucket phases in
// lockstep -> 4 gathers in flight/lane, all from the CURRENT 1.6 MB slice.
template <int F>
__global__ __launch_bounds__(256) void agg_half_kernel(const ushort* __restrict__ h,
                                                       const int* __restrict__ offs2,
                                                       const int* __restrict__ eidx,
                                                       const float* __restrict__ dinv,
                                                       const float* __restrict__ b,
                                                       float* __restrict__ out, int N) {
    constexpr int L = F / 8;
    int tid  = blockIdx.x * 256 + threadIdx.x;
    int pair = tid / L;
    int jw   = tid % L;
    int segA = pair * 2;
    if (segA >= N) return;
    int segB = segA + 1;
    const bool hasB = segB < N;
    const uint4* hv = (const uint4*)h;

    float aA0[8] = {}, aA1[8] = {}, aB0[8] = {}, aB1[8] = {};
    const int baseA = segA * NBKT;
    const int baseB = segB * NBKT;
    int kA = offs2[baseA];
    int kB = hasB ? offs2[baseB] : 0;
#pragma unroll
    for (int q = 0; q < NBKT; ++q) {
        const int eAq = offs2[baseA + q + 1];
        const int eBq = hasB ? offs2[baseB + q + 1] : 0;
        // lockstep: 2 gathers per node in flight, same slice for A and B
        while (kA + 2 <= eAq && kB + 2 <= eBq) {
            int rA0 = eidx[kA], rA1 = eidx[kA + 1];
            int rB0 = eidx[kB], rB1 = eidx[kB + 1];
            uint4 uA0 = hv[(size_t)rA0 * L + jw];
            uint4 uA1 = hv[(size_t)rA1 * L + jw];
            uint4 uB0 = hv[(size_t)rB0 * L + jw];
            uint4 uB1 = hv[(size_t)rB1 * L + jw];
            h8acc(aA0, uA0); h8acc(aA1, uA1); h8acc(aB0, uB0); h8acc(aB1, uB1);
            kA += 2; kB += 2;
        }
        for (; kA + 2 <= eAq; kA += 2) {
            int r0 = eidx[kA], r1 = eidx[kA + 1];
            uint4 u0 = hv[(size_t)r0 * L + jw];
            uint4 u1 = hv[(size_t)r1 * L + jw];
            h8acc(aA0, u0); h8acc(aA1, u1);
        }
        if (kA < eAq) { h8acc(aA0, hv[(size_t)eidx[kA] * L + jw]); ++kA; }
        for (; kB + 2 <= eBq; kB += 2) {
            int r0 = eidx[kB], r1 = eidx[kB + 1];
            uint4 u0 = hv[(size_t)r0 * L + jw];
            uint4 u1 = hv[(size_t)r1 * L + jw];
            h8acc(aB0, u0); h8acc(aB1, u1);
        }
        if (kB < eBq) { h8acc(aB0, hv[(size_t)eidx[kB] * L + jw]); ++kB; }
    }

    // node A epilogue
    h8acc(aA0, hv[(size_t)segA * L + jw]);  // self-loop
#pragma unroll
    for (int i = 0; i < 8; ++i) aA0[i] += aA1[i];
    {
        float  d  = dinv[segA];
        float4 b0 = *(const float4*)&b[jw * 8];
        float4 b1 = *(const float4*)&b[jw * 8 + 4];
        float4 o0 = {b0.x + d * aA0[0], b0.y + d * aA0[1], b0.z + d * aA0[2], b0.w + d * aA0[3]};
        float4 o1 = {b1.x + d * aA0[4], b1.y + d * aA0[5], b1.z + d * aA0[6], b1.w + d * aA0[7]};
        *(float4*)&out[(size_t)segA * F + jw * 8]     = o0;
        *(float4*)&out[(size_t)segA * F + jw * 8 + 4] = o1;
    }
    // node B epilogue
    if (hasB) {
        h8acc(aB0, hv[(size_t)segB * L + jw]);  // self-loop
#pragma unroll
        for (int i = 0; i < 8; ++i) aB0[i] += aB1[i];
        float  d  = dinv[segB];
        float4 b0 = *(const float4*)&b[jw * 8];
        float4 b1 = *(const float4*)&b[jw * 8 + 4];
        float4 o0 = {b0.x + d * aB0[0], b0.y + d * aB0[1], b0.z + d * aB0[2], b0.w + d * aB0[3]};
        float4 o1 = {b1.x + d * aB0[4], b1.y + d * aB0[5], b1.z + d * aB0[6], b1.w + d * aB0[7]};
        *(float4*)&out[(size_t)segB * F + jw * 8]     = o0;
        *(float4*)&out[(size_t)segB * F + jw * 8 + 4] = o1;
    }
}

extern "C" void kernel_launch(void* const* d_in, const int* in_sizes, int n_in,
                              void* d_out, int out_size, void* d_ws, size_t ws_size,
                              hipStream_t stream) {
    const float* x  = (const float*)d_in[0];
    const int*   ei = (const int*)d_in[1];
    const float* W1 = (const float*)d_in[2];
    const float* b1 = (const float*)d_in[3];
    const float* W2 = (const float*)d_in[4];
    const float* b2 = (const float*)d_in[5];
    const float* W3 = (const float*)d_in[6];
    const float* b3 = (const float*)d_in[7];
    const float* W4 = (const float*)d_in[8];
    const float* b4 = (const float*)d_in[9];

    const int N = in_sizes[0] / 128;  // 100000
    const int E = in_sizes[1] / 2;    // 1600000
    const int* row = ei;              // source
    const int* col = ei + E;          // destination
    const int n2   = N * NBKT;
    const int span = (N + NBKT - 1) / NBKT;   // 12500
    const int nsb  = (span + SUBD - 1) / SUBD; // 98

    // ---- workspace layout ----------------------------------------------------
    char* w = (char*)d_ws;
    int*      offs2 = (int*)w;               w += (size_t)(n2 + 4) * 4;
    float*    dinv  = (float*)w;             w += (size_t)N * 4;
    int*      eidx  = (int*)w;               w += (size_t)E * 4;
    unsigned* stag1 = (unsigned*)w;          w += (size_t)NBKT * CAP * 4;  // 8.4 MB
    float*    X     = (float*)w;             w += (size_t)N * 64 * 4;      // 25.6 MB
    ushort*   H     = (ushort*)w;                                          // 12.8 MB
    unsigned* stag2 = (unsigned*)X;
    int*      pcnt2 = (int*)(stag2 + (size_t)NBKT * nsb * CAP2);
    int*      pcnt  = pcnt2 + NBKT * nsb;
    int*      sbase = pcnt + NBKT;
    float*    out   = (float*)d_out;

    const int T  = 256;
    const int NB = (N + T - 1) / T;  // 391

    // ---- CSR build (coalesced-write counting sort) + norm ---------------------
    zero_i32_kernel<<<(NBKT * nsb + NBKT + T - 1) / T, T, 0, stream>>>(pcnt2, NBKT * nsb + NBKT);
    bin_kernel<<<1024, T, 0, stream>>>(row, col, pcnt, stag1, E, span);
    bin2_kernel<<<8 * (CAP / 4096), T, 0, stream>>>(stag1, pcnt, pcnt2, stag2, nsb);
    scan_small_kernel<<<1, 1024, 0, stream>>>(pcnt2, sbase, NBKT * nsb);
    sort_sub_kernel<<<8 * nsb, T, 0, stream>>>(stag2, pcnt2, sbase, offs2, eidx, span, nsb, E);
    dinv2_kernel<<<NB, T, 0, stream>>>(offs2, dinv, N);

    const int g64 = (N + 63) / 64;
    const int g32 = (N + 127) / 128;
    const int npair = (N + 1) / 2;
    const int a64 = (npair * 8 + T - 1) / T;   // 8 lanes per node pair
    const int a32 = (npair * 4 + T - 1) / T;   // 4 lanes per node pair

    // ---- layer 1: x[128] -> 64 ------------------------------------------------
    gemm_tile_kernel<128, 64, false><<<g64, T, 0, stream>>>(x, W1, dinv, H, N);
    agg_half_kernel<64><<<a64, T, 0, stream>>>(H, offs2, eidx, dinv, b1, X, N);
    // ---- layer 2 ----------------------------------------------------------------
    gemm_tile_kernel<64, 64, true><<<g64, T, 0, stream>>>(X, W2, dinv, H, N);
    agg_half_kernel<64><<<a64, T, 0, stream>>>(H, offs2, eidx, dinv, b2, X, N);
    // ---- layer 3 ----------------------------------------------------------------
    gemm_tile_kernel<64, 64, true><<<g64, T, 0, stream>>>(X, W3, dinv, H, N);
    agg_half_kernel<64><<<a64, T, 0, stream>>>(H, offs2, eidx, dinv, b3, X, N);
    // ---- layer 4: 64 -> 32, no ReLU, straight to d_out --------------------------
    gemm_tile_kernel<64, 32, true><<<g32, T, 0, stream>>>(X, W4, dinv, H, N);
    agg_half_kernel<32><<<a32, T, 0, stream>>>(H, offs2, eidx, dinv, b4, out, N);
}

// Round 13
// 312.897 us; speedup vs baseline: 1.3570x; 1.3570x over previous
//
#include <hip/hip_runtime.h>
#include <hip/hip_fp16.h>

// ---------------------------------------------------------------------------
// GCN forward. CSR build = 3-level radix/counting sort with all global writes
// coalesced. Aggregation = one node per lane-group (full TLP, round-12 lesson),
// SINGLE fused loop over the node's bucket-sorted neighbor range (the 8 bucket
// segments are contiguous + sorted, so slice locality is preserved by data
// order), 4-deep load staging (latency regime, fabric unsaturated).
// ---------------------------------------------------------------------------

#define NBKT 8
#define CAP  262144   // per-partition staging cap (E/8 = 200k avg)
#define SUBD 128      // dests per sub-bin
#define CAP2 4096     // per-sub-bin cap (mean 2048, sigma ~45)

__global__ __launch_bounds__(256) void zero_i32_kernel(int* __restrict__ p, int n) {
    int i = blockIdx.x * blockDim.x + threadIdx.x;
    if (i < n) p[i] = 0;
}

// Pass 1: bin edges by dest partition. LDS count -> block bulk-reserve ->
// append packed (r<<14 | c-lo) to stag1[part]. Append-contiguous writes.
__global__ __launch_bounds__(256) void bin_kernel(const int* __restrict__ row,
                                                  const int* __restrict__ col,
                                                  int* __restrict__ pcnt,
                                                  unsigned* __restrict__ stag,
                                                  int E, int span) {
    __shared__ int scnt[NBKT];
    __shared__ int gbase[NBKT];
    const int tid = threadIdx.x;
    for (int base = blockIdx.x * 1024; base < E; base += gridDim.x * 1024) {
        if (tid < NBKT) scnt[tid] = 0;
        __syncthreads();
        int e0 = base + tid * 4;
        unsigned pk[4]; int pt[4], lp[4];
        if (e0 + 4 <= E) {
            int4 r4 = *(const int4*)(row + e0);
            int4 c4 = *(const int4*)(col + e0);
            int rr[4] = {r4.x, r4.y, r4.z, r4.w};
            int cc[4] = {c4.x, c4.y, c4.z, c4.w};
#pragma unroll
            for (int u = 0; u < 4; ++u) {
                int p = cc[u] / span;
                pt[u] = p;
                pk[u] = ((unsigned)rr[u] << 14) | (unsigned)(cc[u] - p * span);
                lp[u] = atomicAdd(&scnt[p], 1);
            }
        } else {
#pragma unroll
            for (int u = 0; u < 4; ++u) {
                int e = e0 + u;
                if (e < E) {
                    int r = row[e], c = col[e];
                    int p = c / span;
                    pt[u] = p;
                    pk[u] = ((unsigned)r << 14) | (unsigned)(c - p * span);
                    lp[u] = atomicAdd(&scnt[p], 1);
                } else pt[u] = -1;
            }
        }
        __syncthreads();
        if (tid < NBKT) gbase[tid] = atomicAdd(&pcnt[tid], scnt[tid]);
        __syncthreads();
#pragma unroll
        for (int u = 0; u < 4; ++u) {
            if (e0 + u < E) {
                stag[(size_t)pt[u] * CAP + (unsigned)(gbase[pt[u]] + lp[u])] = pk[u];
            }
        }
        __syncthreads();
    }
}

// Pass 2: within partition, bin by sub-bin (c_local>>7). Repack (r<<7 | c&127).
__global__ __launch_bounds__(256) void bin2_kernel(const unsigned* __restrict__ stag1,
                                                   const int* __restrict__ pcnt,
                                                   int* __restrict__ pcnt2,
                                                   unsigned* __restrict__ stag2,
                                                   int nsb) {
    __shared__ int scnt[128];
    __shared__ int gbase[128];
    const int part = blockIdx.x & 7;
    const int n = min(pcnt[part], CAP);
    const unsigned* s = stag1 + (size_t)part * CAP;
    const int t0 = (blockIdx.x >> 3) * 4096;
    if (t0 >= n) return;
    const int tn = min(4096, n - t0);
    const int tid = threadIdx.x;

    for (int i = tid; i < nsb; i += 256) scnt[i] = 0;
    __syncthreads();
    for (int i = tid; i < tn; i += 256) {
        unsigned v = s[t0 + i];
        atomicAdd(&scnt[(v & 0x3FFF) >> 7], 1);
    }
    __syncthreads();
    for (int i = tid; i < nsb; i += 256) {
        gbase[i] = atomicAdd(&pcnt2[part * nsb + i], scnt[i]);
        scnt[i] = 0;
    }
    __syncthreads();
    for (int i = tid; i < tn; i += 256) {
        unsigned v = s[t0 + i];
        int cl = v & 0x3FFF;
        int sb = cl >> 7;
        int lp = atomicAdd(&scnt[sb], 1);
        int pos = min(gbase[sb] + lp, CAP2 - 1);  // clamp (never triggers)
        stag2[(size_t)(part * nsb + sb) * CAP2 + pos] = ((v >> 14) << 7) | (unsigned)(cl & 127);
    }
}

// exclusive scan of src[n] -> dst[n], n <= 1024, single block
__global__ __launch_bounds__(1024) void scan_small_kernel(const int* __restrict__ src,
                                                          int* __restrict__ dst, int n) {
    __shared__ int s[1024];
    int tid = threadIdx.x;
    int v = (tid < n) ? src[tid] : 0;
    s[tid] = v;
    __syncthreads();
    for (int off = 1; off < 1024; off <<= 1) {
        int t = (tid >= off) ? s[tid - off] : 0;
        __syncthreads();
        s[tid] += t;
        __syncthreads();
    }
    if (tid < n) dst[tid] = s[tid] - v;
}

// Pass 3: one workgroup per sub-bin. LDS counting sort over 1024 keys
// (c_local7 * 8 + src_bucket); writes offs2 segment + sorted eidx coalesced.
__global__ __launch_bounds__(256) void sort_sub_kernel(const unsigned* __restrict__ stag2,
                                                       const int* __restrict__ pcnt2,
                                                       const int* __restrict__ sbase,
                                                       int* __restrict__ offs2,
                                                       int* __restrict__ eidx,
                                                       int span, int nsb, int E) {
    __shared__ int cnt[1024];
    __shared__ int tsum[256];
    __shared__ int lout[CAP2];
    const int part = blockIdx.x & 7;
    const int sb   = blockIdx.x >> 3;
    if (sb >= nsb) return;
    const int sbg  = part * nsb + sb;
    const int n    = min(pcnt2[sbg], CAP2);
    const unsigned* s = stag2 + (size_t)sbg * CAP2;
    const int base = sbase[sbg];
    const int c0   = part * span + sb * SUBD;
    const int dd   = min(SUBD, span - sb * SUBD);
    const int tid  = threadIdx.x;

    for (int i = tid; i < 1024; i += 256) cnt[i] = 0;
    __syncthreads();
    for (int i = tid; i < n; i += 256) {
        unsigned v = s[i];
        int r = v >> 7;
        atomicAdd(&cnt[((v & 127) << 3) | (r / span)], 1);
    }
    __syncthreads();
    int a0 = cnt[tid * 4], a1 = cnt[tid * 4 + 1], a2 = cnt[tid * 4 + 2], a3 = cnt[tid * 4 + 3];
    int tot = a0 + a1 + a2 + a3;
    tsum[tid] = tot;
    __syncthreads();
    for (int off = 1; off < 256; off <<= 1) {
        int t = (tid >= off) ? tsum[tid - off] : 0;
        __syncthreads();
        tsum[tid] += t;
        __syncthreads();
    }
    int pre = tsum[tid] - tot;
    cnt[tid * 4]     = pre;
    cnt[tid * 4 + 1] = pre + a0;
    cnt[tid * 4 + 2] = pre + a0 + a1;
    cnt[tid * 4 + 3] = pre + a0 + a1 + a2;
    __syncthreads();
    for (int k = tid; k < dd * 8; k += 256) offs2[(size_t)c0 * 8 + k] = base + cnt[k];
    if (part == NBKT - 1 && sb == nsb - 1 && tid == 0) offs2[(size_t)(c0 + dd) * 8] = base + n;
    __syncthreads();
    for (int i = tid; i < n; i += 256) {
        unsigned v = s[i];
        int r = v >> 7;
        int p = atomicAdd(&cnt[((v & 127) << 3) | (r / span)], 1);
        lout[p] = r;
    }
    __syncthreads();
    for (int i = tid; i < n; i += 256) eidx[base + i] = lout[i];
}

__global__ __launch_bounds__(256) void dinv2_kernel(const int* __restrict__ offs2,
                                                    float* __restrict__ dinv, int N) {
    int i = blockIdx.x * blockDim.x + threadIdx.x;
    if (i < N) {
        int deg = offs2[i * NBKT + NBKT] - offs2[i * NBKT];
        dinv[i] = rsqrtf((float)deg + 1.0f);  // +1 self-loop
    }
}

// H(fp16) = ((RELU? relu(in) : in) @ W) * dinv[row].  W is [F_IN,F_OUT] rowmaj.
template <int F_IN, int F_OUT, bool RELU>
__global__ __launch_bounds__(256, 4) void gemm_tile_kernel(const float* __restrict__ in,
                                                           const float* __restrict__ W,
                                                           const float* __restrict__ dinv,
                                                           ushort* __restrict__ outh, int N) {
    constexpr int TC   = F_OUT / 4;
    constexpr int TR   = 256 / TC;
    constexpr int ROWS = TR * 4;
    constexpr int NKB  = F_IN / 64;
    __shared__ float sIn[ROWS][68];
    __shared__ float sW[64][F_OUT];

    const int tc = threadIdx.x % TC;
    const int tr = threadIdx.x / TC;
    const int r0 = blockIdx.x * ROWS;

    float acc[4][4] = {};

#pragma unroll
    for (int kb = 0; kb < NKB; ++kb) {
        if (kb) __syncthreads();
        for (int idx = threadIdx.x; idx < ROWS * 16; idx += 256) {
            int rr = idx / 16, c4 = (idx % 16) * 4;
            int gr = min(r0 + rr, N - 1);
            float4 v = *(const float4*)&in[(size_t)gr * F_IN + kb * 64 + c4];
            if (RELU) {
                v.x = fmaxf(v.x, 0.f); v.y = fmaxf(v.y, 0.f);
                v.z = fmaxf(v.z, 0.f); v.w = fmaxf(v.w, 0.f);
            }
            *(float4*)&sIn[rr][c4] = v;
        }
        for (int idx = threadIdx.x; idx < 64 * F_OUT / 4; idx += 256) {
            int kr = idx / (F_OUT / 4), c4 = (idx % (F_OUT / 4)) * 4;
            *(float4*)&sW[kr][c4] = *(const float4*)&W[(size_t)(kb * 64 + kr) * F_OUT + c4];
        }
        __syncthreads();
#pragma unroll 2
        for (int kk = 0; kk < 64; kk += 4) {
            float4 iv[4], wv[4];
#pragma unroll
            for (int i = 0; i < 4; ++i) iv[i] = *(const float4*)&sIn[tr * 4 + i][kk];
#pragma unroll
            for (int q = 0; q < 4; ++q) wv[q] = *(const float4*)&sW[kk + q][tc * 4];
#pragma unroll
            for (int i = 0; i < 4; ++i) {
                const float ik[4] = {iv[i].x, iv[i].y, iv[i].z, iv[i].w};
#pragma unroll
                for (int q = 0; q < 4; ++q) {
                    acc[i][0] = fmaf(ik[q], wv[q].x, acc[i][0]);
                    acc[i][1] = fmaf(ik[q], wv[q].y, acc[i][1]);
                    acc[i][2] = fmaf(ik[q], wv[q].z, acc[i][2]);
                    acc[i][3] = fmaf(ik[q], wv[q].w, acc[i][3]);
                }
            }
        }
    }
#pragma unroll
    for (int i = 0; i < 4; ++i) {
        int r = r0 + tr * 4 + i;
        if (r < N) {
            float d = dinv[r];
            ushort4 v;
            v.x = __half_as_ushort(__float2half(acc[i][0] * d));
            v.y = __half_as_ushort(__float2half(acc[i][1] * d));
            v.z = __half_as_ushort(__float2half(acc[i][2] * d));
            v.w = __half_as_ushort(__float2half(acc[i][3] * d));
            *(ushort4*)&outh[(size_t)r * F_OUT + tc * 4] = v;
        }
    }
}

__device__ inline void h8acc(float* acc, uint4 u) {
    const __half2* p = (const __half2*)&u;
#pragma unroll
    for (int i = 0; i < 4; ++i) {
        float2 f = __half22float2(p[i]);
        acc[2 * i]     += f.x;
        acc[2 * i + 1] += f.y;
    }
}

// out[c, jw*8..+7] = b + dinv[c]*( sum_{neighbors} H16[r] + H16[c] )
// One node per lane group (full TLP). Single fused loop over the contiguous,
// bucket-sorted neighbor range [offs2[c*8], offs2[c*8+8]) -- slice locality
// comes from the eidx ordering; no per-bucket boundaries. 4 loads staged.
template <int F>
__global__ __launch_bounds__(256) void agg_half_kernel(const ushort* __restrict__ h,
                                                       const int* __restrict__ offs2,
                                                       const int* __restrict__ eidx,
                                                       const float* __restrict__ dinv,
                                                       const float* __restrict__ b,
                                                       float* __restrict__ out, int N) {
    constexpr int L = F / 8;
    int tid = blockIdx.x * 256 + threadIdx.x;
    int seg = tid / L;
    int jw  = tid % L;
    if (seg >= N) return;
    const uint4* hv = (const uint4*)h;

    int k = offs2[(size_t)seg * NBKT];
    const int e = offs2[(size_t)seg * NBKT + NBKT];

    float a0[8] = {}, a1[8] = {};
    for (; k + 4 <= e; k += 4) {
        int r0 = eidx[k], r1 = eidx[k + 1], r2 = eidx[k + 2], r3 = eidx[k + 3];
        uint4 u0 = hv[(size_t)r0 * L + jw];
        uint4 u1 = hv[(size_t)r1 * L + jw];
        uint4 u2 = hv[(size_t)r2 * L + jw];
        uint4 u3 = hv[(size_t)r3 * L + jw];
        h8acc(a0, u0); h8acc(a1, u1); h8acc(a0, u2); h8acc(a1, u3);
    }
    if (k + 2 <= e) {
        int r0 = eidx[k], r1 = eidx[k + 1];
        uint4 u0 = hv[(size_t)r0 * L + jw];
        uint4 u1 = hv[(size_t)r1 * L + jw];
        h8acc(a0, u0); h8acc(a1, u1);
        k += 2;
    }
    if (k < e) h8acc(a0, hv[(size_t)eidx[k] * L + jw]);

    h8acc(a0, hv[(size_t)seg * L + jw]);  // self-loop
#pragma unroll
    for (int i = 0; i < 8; ++i) a0[i] += a1[i];

    float  d  = dinv[seg];
    float4 b0 = *(const float4*)&b[jw * 8];
    float4 b1 = *(const float4*)&b[jw * 8 + 4];
    float4 o0 = {b0.x + d * a0[0], b0.y + d * a0[1], b0.z + d * a0[2], b0.w + d * a0[3]};
    float4 o1 = {b1.x + d * a0[4], b1.y + d * a0[5], b1.z + d * a0[6], b1.w + d * a0[7]};
    *(float4*)&out[(size_t)seg * F + jw * 8]     = o0;
    *(float4*)&out[(size_t)seg * F + jw * 8 + 4] = o1;
}

extern "C" void kernel_launch(void* const* d_in, const int* in_sizes, int n_in,
                              void* d_out, int out_size, void* d_ws, size_t ws_size,
                              hipStream_t stream) {
    const float* x  = (const float*)d_in[0];
    const int*   ei = (const int*)d_in[1];
    const float* W1 = (const float*)d_in[2];
    const float* b1 = (const float*)d_in[3];
    const float* W2 = (const float*)d_in[4];
    const float* b2 = (const float*)d_in[5];
    const float* W3 = (const float*)d_in[6];
    const float* b3 = (const float*)d_in[7];
    const float* W4 = (const float*)d_in[8];
    const float* b4 = (const float*)d_in[9];

    const int N = in_sizes[0] / 128;  // 100000
    const int E = in_sizes[1] / 2;    // 1600000
    const int* row = ei;              // source
    const int* col = ei + E;          // destination
    const int n2   = N * NBKT;
    const int span = (N + NBKT - 1) / NBKT;   // 12500
    const int nsb  = (span + SUBD - 1) / SUBD; // 98

    // ---- workspace layout ----------------------------------------------------
    char* w = (char*)d_ws;
    int*      offs2 = (int*)w;               w += (size_t)(n2 + 4) * 4;
    float*    dinv  = (float*)w;             w += (size_t)N * 4;
    int*      eidx  = (int*)w;               w += (size_t)E * 4;
    unsigned* stag1 = (unsigned*)w;          w += (size_t)NBKT * CAP * 4;  // 8.4 MB
    float*    X     = (float*)w;             w += (size_t)N * 64 * 4;      // 25.6 MB
    ushort*   H     = (ushort*)w;                                          // 12.8 MB
    unsigned* stag2 = (unsigned*)X;
    int*      pcnt2 = (int*)(stag2 + (size_t)NBKT * nsb * CAP2);
    int*      pcnt  = pcnt2 + NBKT * nsb;
    int*      sbase = pcnt + NBKT;
    float*    out   = (float*)d_out;

    const int T  = 256;
    const int NB = (N + T - 1) / T;  // 391

    // ---- CSR build (coalesced-write counting sort) + norm ---------------------
    zero_i32_kernel<<<(NBKT * nsb + NBKT + T - 1) / T, T, 0, stream>>>(pcnt2, NBKT * nsb + NBKT);
    bin_kernel<<<1024, T, 0, stream>>>(row, col, pcnt, stag1, E, span);
    bin2_kernel<<<8 * (CAP / 4096), T, 0, stream>>>(stag1, pcnt, pcnt2, stag2, nsb);
    scan_small_kernel<<<1, 1024, 0, stream>>>(pcnt2, sbase, NBKT * nsb);
    sort_sub_kernel<<<8 * nsb, T, 0, stream>>>(stag2, pcnt2, sbase, offs2, eidx, span, nsb, E);
    dinv2_kernel<<<NB, T, 0, stream>>>(offs2, dinv, N);

    const int g64 = (N + 63) / 64;
    const int g32 = (N + 127) / 128;
    const int a64 = (N * 8 + T - 1) / T;   // 8 lanes per node
    const int a32 = (N * 4 + T - 1) / T;   // 4 lanes per node

    // ---- layer 1: x[128] -> 64 ------------------------------------------------
    gemm_tile_kernel<128, 64, false><<<g64, T, 0, stream>>>(x, W1, dinv, H, N);
    agg_half_kernel<64><<<a64, T, 0, stream>>>(H, offs2, eidx, dinv, b1, X, N);
    // ---- layer 2 ----------------------------------------------------------------
    gemm_tile_kernel<64, 64, true><<<g64, T, 0, stream>>>(X, W2, dinv, H, N);
    agg_half_kernel<64><<<a64, T, 0, stream>>>(H, offs2, eidx, dinv, b2, X, N);
    // ---- layer 3 ----------------------------------------------------------------
    gemm_tile_kernel<64, 64, true><<<g64, T, 0, stream>>>(X, W3, dinv, H, N);
    agg_half_kernel<64><<<a64, T, 0, stream>>>(H, offs2, eidx, dinv, b3, X, N);
    // ---- layer 4: 64 -> 32, no ReLU, straight to d_out --------------------------
    gemm_tile_kernel<64, 32, true><<<g32, T, 0, stream>>>(X, W4, dinv, H, N);
    agg_half_kernel<32><<<a32, T, 0, stream>>>(H, offs2, eidx, dinv, b4, out, N);
}

// Round 14
// 301.459 us; speedup vs baseline: 1.4085x; 1.0379x over previous
//
#include <hip/hip_runtime.h>
#include <hip/hip_fp16.h>

// ---------------------------------------------------------------------------
// GCN forward. CSR build = 3-level radix/counting sort (coalesced writes).
// Layers fused: each block aggregates its GEMM tile's dest rows (round-13
// gather loop) directly into the LDS input tile (bias+ReLU), then runs the
// register-tiled GEMM. X (f32, 25.6MB) is never materialized; H ping-pongs
// in fp16.  Sequence:
//   gemm1: H1 = (x @ W1) * dinv
//   fused2: relu(b1 + dinv*aggH1) @ W2 * dinv -> H2
//   fused3: relu(b2 + dinv*aggH2) @ W3 * dinv -> H3
//   fused4: relu(b3 + dinv*aggH3) @ W4 * dinv -> H4   (F_OUT=32)
//   agg32 : b4 + dinv*aggH4 -> d_out
// ---------------------------------------------------------------------------

#define NBKT 8
#define CAP  262144   // per-partition staging cap (E/8 = 200k avg)
#define SUBD 128      // dests per sub-bin
#define CAP2 4096     // per-sub-bin cap (mean 2048, sigma ~45)

__global__ __launch_bounds__(256) void zero_i32_kernel(int* __restrict__ p, int n) {
    int i = blockIdx.x * blockDim.x + threadIdx.x;
    if (i < n) p[i] = 0;
}

// Pass 1: bin edges by dest partition. LDS count -> block bulk-reserve ->
// append packed (r<<14 | c-lo) to stag1[part]. Append-contiguous writes.
__global__ __launch_bounds__(256) void bin_kernel(const int* __restrict__ row,
                                                  const int* __restrict__ col,
                                                  int* __restrict__ pcnt,
                                                  unsigned* __restrict__ stag,
                                                  int E, int span) {
    __shared__ int scnt[NBKT];
    __shared__ int gbase[NBKT];
    const int tid = threadIdx.x;
    for (int base = blockIdx.x * 1024; base < E; base += gridDim.x * 1024) {
        if (tid < NBKT) scnt[tid] = 0;
        __syncthreads();
        int e0 = base + tid * 4;
        unsigned pk[4]; int pt[4], lp[4];
        if (e0 + 4 <= E) {
            int4 r4 = *(const int4*)(row + e0);
            int4 c4 = *(const int4*)(col + e0);
            int rr[4] = {r4.x, r4.y, r4.z, r4.w};
            int cc[4] = {c4.x, c4.y, c4.z, c4.w};
#pragma unroll
            for (int u = 0; u < 4; ++u) {
                int p = cc[u] / span;
                pt[u] = p;
                pk[u] = ((unsigned)rr[u] << 14) | (unsigned)(cc[u] - p * span);
                lp[u] = atomicAdd(&scnt[p], 1);
            }
        } else {
#pragma unroll
            for (int u = 0; u < 4; ++u) {
                int e = e0 + u;
                if (e < E) {
                    int r = row[e], c = col[e];
                    int p = c / span;
                    pt[u] = p;
                    pk[u] = ((unsigned)r << 14) | (unsigned)(c - p * span);
                    lp[u] = atomicAdd(&scnt[p], 1);
                } else pt[u] = -1;
            }
        }
        __syncthreads();
        if (tid < NBKT) gbase[tid] = atomicAdd(&pcnt[tid], scnt[tid]);
        __syncthreads();
#pragma unroll
        for (int u = 0; u < 4; ++u) {
            if (e0 + u < E) {
                stag[(size_t)pt[u] * CAP + (unsigned)(gbase[pt[u]] + lp[u])] = pk[u];
            }
        }
        __syncthreads();
    }
}

// Pass 2: within partition, bin by sub-bin (c_local>>7). Repack (r<<7 | c&127).
__global__ __launch_bounds__(256) void bin2_kernel(const unsigned* __restrict__ stag1,
                                                   const int* __restrict__ pcnt,
                                                   int* __restrict__ pcnt2,
                                                   unsigned* __restrict__ stag2,
                                                   int nsb) {
    __shared__ int scnt[128];
    __shared__ int gbase[128];
    const int part = blockIdx.x & 7;
    const int n = min(pcnt[part], CAP);
    const unsigned* s = stag1 + (size_t)part * CAP;
    const int t0 = (blockIdx.x >> 3) * 4096;
    if (t0 >= n) return;
    const int tn = min(4096, n - t0);
    const int tid = threadIdx.x;

    for (int i = tid; i < nsb; i += 256) scnt[i] = 0;
    __syncthreads();
    for (int i = tid; i < tn; i += 256) {
        unsigned v = s[t0 + i];
        atomicAdd(&scnt[(v & 0x3FFF) >> 7], 1);
    }
    __syncthreads();
    for (int i = tid; i < nsb; i += 256) {
        gbase[i] = atomicAdd(&pcnt2[part * nsb + i], scnt[i]);
        scnt[i] = 0;
    }
    __syncthreads();
    for (int i = tid; i < tn; i += 256) {
        unsigned v = s[t0 + i];
        int cl = v & 0x3FFF;
        int sb = cl >> 7;
        int lp = atomicAdd(&scnt[sb], 1);
        int pos = min(gbase[sb] + lp, CAP2 - 1);  // clamp (never triggers)
        stag2[(size_t)(part * nsb + sb) * CAP2 + pos] = ((v >> 14) << 7) | (unsigned)(cl & 127);
    }
}

// exclusive scan of src[n] -> dst[n], n <= 1024, single block
__global__ __launch_bounds__(1024) void scan_small_kernel(const int* __restrict__ src,
                                                          int* __restrict__ dst, int n) {
    __shared__ int s[1024];
    int tid = threadIdx.x;
    int v = (tid < n) ? src[tid] : 0;
    s[tid] = v;
    __syncthreads();
    for (int off = 1; off < 1024; off <<= 1) {
        int t = (tid >= off) ? s[tid - off] : 0;
        __syncthreads();
        s[tid] += t;
        __syncthreads();
    }
    if (tid < n) dst[tid] = s[tid] - v;
}

// Pass 3: one workgroup per sub-bin. LDS counting sort over 1024 keys
// (c_local7 * 8 + src_bucket); writes offs2 segment + sorted eidx coalesced.
__global__ __launch_bounds__(256) void sort_sub_kernel(const unsigned* __restrict__ stag2,
                                                       const int* __restrict__ pcnt2,
                                                       const int* __restrict__ sbase,
                                                       int* __restrict__ offs2,
                                                       int* __restrict__ eidx,
                                                       int span, int nsb, int E) {
    __shared__ int cnt[1024];
    __shared__ int tsum[256];
    __shared__ int lout[CAP2];
    const int part = blockIdx.x & 7;
    const int sb   = blockIdx.x >> 3;
    if (sb >= nsb) return;
    const int sbg  = part * nsb + sb;
    const int n    = min(pcnt2[sbg], CAP2);
    const unsigned* s = stag2 + (size_t)sbg * CAP2;
    const int base = sbase[sbg];
    const int c0   = part * span + sb * SUBD;
    const int dd   = min(SUBD, span - sb * SUBD);
    const int tid  = threadIdx.x;

    for (int i = tid; i < 1024; i += 256) cnt[i] = 0;
    __syncthreads();
    for (int i = tid; i < n; i += 256) {
        unsigned v = s[i];
        int r = v >> 7;
        atomicAdd(&cnt[((v & 127) << 3) | (r / span)], 1);
    }
    __syncthreads();
    int a0 = cnt[tid * 4], a1 = cnt[tid * 4 + 1], a2 = cnt[tid * 4 + 2], a3 = cnt[tid * 4 + 3];
    int tot = a0 + a1 + a2 + a3;
    tsum[tid] = tot;
    __syncthreads();
    for (int off = 1; off < 256; off <<= 1) {
        int t = (tid >= off) ? tsum[tid - off] : 0;
        __syncthreads();
        tsum[tid] += t;
        __syncthreads();
    }
    int pre = tsum[tid] - tot;
    cnt[tid * 4]     = pre;
    cnt[tid * 4 + 1] = pre + a0;
    cnt[tid * 4 + 2] = pre + a0 + a1;
    cnt[tid * 4 + 3] = pre + a0 + a1 + a2;
    __syncthreads();
    for (int k = tid; k < dd * 8; k += 256) offs2[(size_t)c0 * 8 + k] = base + cnt[k];
    if (part == NBKT - 1 && sb == nsb - 1 && tid == 0) offs2[(size_t)(c0 + dd) * 8] = base + n;
    __syncthreads();
    for (int i = tid; i < n; i += 256) {
        unsigned v = s[i];
        int r = v >> 7;
        int p = atomicAdd(&cnt[((v & 127) << 3) | (r / span)], 1);
        lout[p] = r;
    }
    __syncthreads();
    for (int i = tid; i < n; i += 256) eidx[base + i] = lout[i];
}

__global__ __launch_bounds__(256) void dinv2_kernel(const int* __restrict__ offs2,
                                                    float* __restrict__ dinv, int N) {
    int i = blockIdx.x * blockDim.x + threadIdx.x;
    if (i < N) {
        int deg = offs2[i * NBKT + NBKT] - offs2[i * NBKT];
        dinv[i] = rsqrtf((float)deg + 1.0f);  // +1 self-loop
    }
}

// H(fp16) = ((RELU? relu(in) : in) @ W) * dinv[row].  W is [F_IN,F_OUT] rowmaj.
// Used only for layer 1 (x f32 input).
template <int F_IN, int F_OUT, bool RELU>
__global__ __launch_bounds__(256, 4) void gemm_tile_kernel(const float* __restrict__ in,
                                                           const float* __restrict__ W,
                                                           const float* __restrict__ dinv,
                                                           ushort* __restrict__ outh, int N) {
    constexpr int TC   = F_OUT / 4;
    constexpr int TR   = 256 / TC;
    constexpr int ROWS = TR * 4;
    constexpr int NKB  = F_IN / 64;
    __shared__ float sIn[ROWS][68];
    __shared__ float sW[64][F_OUT];

    const int tc = threadIdx.x % TC;
    const int tr = threadIdx.x / TC;
    const int r0 = blockIdx.x * ROWS;

    float acc[4][4] = {};

#pragma unroll
    for (int kb = 0; kb < NKB; ++kb) {
        if (kb) __syncthreads();
        for (int idx = threadIdx.x; idx < ROWS * 16; idx += 256) {
            int rr = idx / 16, c4 = (idx % 16) * 4;
            int gr = min(r0 + rr, N - 1);
            float4 v = *(const float4*)&in[(size_t)gr * F_IN + kb * 64 + c4];
            if (RELU) {
                v.x = fmaxf(v.x, 0.f); v.y = fmaxf(v.y, 0.f);
                v.z = fmaxf(v.z, 0.f); v.w = fmaxf(v.w, 0.f);
            }
            *(float4*)&sIn[rr][c4] = v;
        }
        for (int idx = threadIdx.x; idx < 64 * F_OUT / 4; idx += 256) {
            int kr = idx / (F_OUT / 4), c4 = (idx % (F_OUT / 4)) * 4;
            *(float4*)&sW[kr][c4] = *(const float4*)&W[(size_t)(kb * 64 + kr) * F_OUT + c4];
        }
        __syncthreads();
#pragma unroll 2
        for (int kk = 0; kk < 64; kk += 4) {
            float4 iv[4], wv[4];
#pragma unroll
            for (int i = 0; i < 4; ++i) iv[i] = *(const float4*)&sIn[tr * 4 + i][kk];
#pragma unroll
            for (int q = 0; q < 4; ++q) wv[q] = *(const float4*)&sW[kk + q][tc * 4];
#pragma unroll
            for (int i = 0; i < 4; ++i) {
                const float ik[4] = {iv[i].x, iv[i].y, iv[i].z, iv[i].w};
#pragma unroll
                for (int q = 0; q < 4; ++q) {
                    acc[i][0] = fmaf(ik[q], wv[q].x, acc[i][0]);
                    acc[i][1] = fmaf(ik[q], wv[q].y, acc[i][1]);
                    acc[i][2] = fmaf(ik[q], wv[q].z, acc[i][2]);
                    acc[i][3] = fmaf(ik[q], wv[q].w, acc[i][3]);
                }
            }
        }
    }
#pragma unroll
    for (int i = 0; i < 4; ++i) {
        int r = r0 + tr * 4 + i;
        if (r < N) {
            float d = dinv[r];
            ushort4 v;
            v.x = __half_as_ushort(__float2half(acc[i][0] * d));
            v.y = __half_as_ushort(__float2half(acc[i][1] * d));
            v.z = __half_as_ushort(__float2half(acc[i][2] * d));
            v.w = __half_as_ushort(__float2half(acc[i][3] * d));
            *(ushort4*)&outh[(size_t)r * F_OUT + tc * 4] = v;
        }
    }
}

__device__ inline void h8acc(float* acc, uint4 u) {
    const __half2* p = (const __half2*)&u;
#pragma unroll
    for (int i = 0; i < 4; ++i) {
        float2 f = __half22float2(p[i]);
        acc[2 * i]     += f.x;
        acc[2 * i + 1] += f.y;
    }
}

// Fused layer: block owns ROWS dest nodes. Phase 1: aggregate each node's
// neighbors from hin (round-13 gather loop, 8 lanes/node, 32 nodes/pass),
// apply bias_prev + dinv + ReLU, write row to LDS. Phase 2: GEMM with W.
template <int F_OUT>
__global__ __launch_bounds__(256, 4) void fused_agg_gemm_kernel(
    const ushort* __restrict__ hin,      // N x 64 fp16 (pre-scaled by dinv[src])
    const int* __restrict__ offs2,
    const int* __restrict__ eidx,
    const float* __restrict__ dinv,
    const float* __restrict__ bias,      // bias of the PREVIOUS conv (64)
    const float* __restrict__ W,         // 64 x F_OUT
    ushort* __restrict__ hout, int N) {
    constexpr int TC   = F_OUT / 4;      // 16 or 8
    constexpr int TR   = 256 / TC;       // 16 or 32
    constexpr int ROWS = TR * 4;         // 64 or 128
    constexpr int L    = 8;              // uint4s per 64-wide fp16 row
    __shared__ float sIn[ROWS][68];
    __shared__ float sW[64][F_OUT];

    const int tid = threadIdx.x;
    const int r0  = blockIdx.x * ROWS;
    const uint4* hv = (const uint4*)hin;

    // ---- phase 1: aggregate ROWS nodes, 32 nodes per pass --------------------
    const int jw  = tid & 7;
    const int grp = tid >> 3;            // 0..31
    float bj[8];
#pragma unroll
    for (int i = 0; i < 8; ++i) bj[i] = bias[jw * 8 + i];

#pragma unroll
    for (int pass = 0; pass < ROWS / 32; ++pass) {
        int rl  = pass * 32 + grp;
        int seg = r0 + rl;
        if (seg < N) {
            float a0[8] = {}, a1[8] = {};
            int k = offs2[(size_t)seg * NBKT];
            const int e = offs2[(size_t)seg * NBKT + NBKT];
            for (; k + 4 <= e; k += 4) {
                int s0 = eidx[k], s1 = eidx[k + 1], s2 = eidx[k + 2], s3 = eidx[k + 3];
                uint4 u0 = hv[(size_t)s0 * L + jw];
                uint4 u1 = hv[(size_t)s1 * L + jw];
                uint4 u2 = hv[(size_t)s2 * L + jw];
                uint4 u3 = hv[(size_t)s3 * L + jw];
                h8acc(a0, u0); h8acc(a1, u1); h8acc(a0, u2); h8acc(a1, u3);
            }
            if (k + 2 <= e) {
                int s0 = eidx[k], s1 = eidx[k + 1];
                uint4 u0 = hv[(size_t)s0 * L + jw];
                uint4 u1 = hv[(size_t)s1 * L + jw];
                h8acc(a0, u0); h8acc(a1, u1);
                k += 2;
            }
            if (k < e) h8acc(a0, hv[(size_t)eidx[k] * L + jw]);
            h8acc(a0, hv[(size_t)seg * L + jw]);  // self-loop
            float d = dinv[seg];
#pragma unroll
            for (int i = 0; i < 8; ++i) {
                float v = bj[i] + d * (a0[i] + a1[i]);
                sIn[rl][jw * 8 + i] = fmaxf(v, 0.0f);   // ReLU
            }
        } else {
#pragma unroll
            for (int i = 0; i < 8; ++i) sIn[rl][jw * 8 + i] = 0.0f;
        }
    }
    // ---- stage W --------------------------------------------------------------
    for (int idx = tid; idx < 64 * F_OUT / 4; idx += 256) {
        int kr = idx / (F_OUT / 4), c4 = (idx % (F_OUT / 4)) * 4;
        *(float4*)&sW[kr][c4] = *(const float4*)&W[(size_t)kr * F_OUT + c4];
    }
    __syncthreads();

    // ---- phase 2: GEMM --------------------------------------------------------
    const int tc = tid % TC;
    const int tr = tid / TC;
    float acc[4][4] = {};
#pragma unroll 2
    for (int kk = 0; kk < 64; kk += 4) {
        float4 iv[4], wv[4];
#pragma unroll
        for (int i = 0; i < 4; ++i) iv[i] = *(const float4*)&sIn[tr * 4 + i][kk];
#pragma unroll
        for (int q = 0; q < 4; ++q) wv[q] = *(const float4*)&sW[kk + q][tc * 4];
#pragma unroll
        for (int i = 0; i < 4; ++i) {
            const float ik[4] = {iv[i].x, iv[i].y, iv[i].z, iv[i].w};
#pragma unroll
            for (int q = 0; q < 4; ++q) {
                acc[i][0] = fmaf(ik[q], wv[q].x, acc[i][0]);
                acc[i][1] = fmaf(ik[q], wv[q].y, acc[i][1]);
                acc[i][2] = fmaf(ik[q], wv[q].z, acc[i][2]);
                acc[i][3] = fmaf(ik[q], wv[q].w, acc[i][3]);
            }
        }
    }
#pragma unroll
    for (int i = 0; i < 4; ++i) {
        int r = r0 + tr * 4 + i;
        if (r < N) {
            float d = dinv[r];
            ushort4 v;
            v.x = __half_as_ushort(__float2half(acc[i][0] * d));
            v.y = __half_as_ushort(__float2half(acc[i][1] * d));
            v.z = __half_as_ushort(__float2half(acc[i][2] * d));
            v.w = __half_as_ushort(__float2half(acc[i][3] * d));
            *(ushort4*)&hout[(size_t)r * F_OUT + tc * 4] = v;
        }
    }
}

// Final: out[c] = b + dinv[c]*( sum_{neighbors} H16[r] + H16[c] ), f32 out.
template <int F>
__global__ __launch_bounds__(256) void agg_half_kernel(const ushort* __restrict__ h,
                                                       const int* __restrict__ offs2,
                                                       const int* __restrict__ eidx,
                                                       const float* __restrict__ dinv,
                                                       const float* __restrict__ b,
                                                       float* __restrict__ out, int N) {
    constexpr int L = F / 8;
    int tid = blockIdx.x * 256 + threadIdx.x;
    int seg = tid / L;
    int jw  = tid % L;
    if (seg >= N) return;
    const uint4* hv = (const uint4*)h;

    int k = offs2[(size_t)seg * NBKT];
    const int e = offs2[(size_t)seg * NBKT + NBKT];

    float a0[8] = {}, a1[8] = {};
    for (; k + 4 <= e; k += 4) {
        int r0 = eidx[k], r1 = eidx[k + 1], r2 = eidx[k + 2], r3 = eidx[k + 3];
        uint4 u0 = hv[(size_t)r0 * L + jw];
        uint4 u1 = hv[(size_t)r1 * L + jw];
        uint4 u2 = hv[(size_t)r2 * L + jw];
        uint4 u3 = hv[(size_t)r3 * L + jw];
        h8acc(a0, u0); h8acc(a1, u1); h8acc(a0, u2); h8acc(a1, u3);
    }
    if (k + 2 <= e) {
        int r0 = eidx[k], r1 = eidx[k + 1];
        uint4 u0 = hv[(size_t)r0 * L + jw];
        uint4 u1 = hv[(size_t)r1 * L + jw];
        h8acc(a0, u0); h8acc(a1, u1);
        k += 2;
    }
    if (k < e) h8acc(a0, hv[(size_t)eidx[k] * L + jw]);

    h8acc(a0, hv[(size_t)seg * L + jw]);  // self-loop
#pragma unroll
    for (int i = 0; i < 8; ++i) a0[i] += a1[i];

    float  d  = dinv[seg];
    float4 b0 = *(const float4*)&b[jw * 8];
    float4 b1 = *(const float4*)&b[jw * 8 + 4];
    float4 o0 = {b0.x + d * a0[0], b0.y + d * a0[1], b0.z + d * a0[2], b0.w + d * a0[3]};
    float4 o1 = {b1.x + d * a0[4], b1.y + d * a0[5], b1.z + d * a0[6], b1.w + d * a0[7]};
    *(float4*)&out[(size_t)seg * F + jw * 8]     = o0;
    *(float4*)&out[(size_t)seg * F + jw * 8 + 4] = o1;
}

extern "C" void kernel_launch(void* const* d_in, const int* in_sizes, int n_in,
                              void* d_out, int out_size, void* d_ws, size_t ws_size,
                              hipStream_t stream) {
    const float* x  = (const float*)d_in[0];
    const int*   ei = (const int*)d_in[1];
    const float* W1 = (const float*)d_in[2];
    const float* b1 = (const float*)d_in[3];
    const float* W2 = (const float*)d_in[4];
    const float* b2 = (const float*)d_in[5];
    const float* W3 = (const float*)d_in[6];
    const float* b3 = (const float*)d_in[7];
    const float* W4 = (const float*)d_in[8];
    const float* b4 = (const float*)d_in[9];

    const int N = in_sizes[0] / 128;  // 100000
    const int E = in_sizes[1] / 2;    // 1600000
    const int* row = ei;              // source
    const int* col = ei + E;          // destination
    const int n2   = N * NBKT;
    const int span = (N + NBKT - 1) / NBKT;   // 12500
    const int nsb  = (span + SUBD - 1) / SUBD; // 98

    // ---- workspace layout ----------------------------------------------------
    // persistent: offs2, dinv, eidx, stag1, HA, HB (fp16 ping-pong)
    // transient:  stag2/pcnt2/pcnt/sbase alias HA+HB (dead before gemm1/fused2)
    char* w = (char*)d_ws;
    int*      offs2 = (int*)w;               w += (size_t)(n2 + 4) * 4;
    float*    dinv  = (float*)w;             w += (size_t)N * 4;
    int*      eidx  = (int*)w;               w += (size_t)E * 4;
    unsigned* stag1 = (unsigned*)w;          w += (size_t)NBKT * CAP * 4;  // 8.4 MB
    ushort*   HA    = (ushort*)w;            w += (size_t)N * 64 * 2;      // 12.8 MB
    ushort*   HB    = (ushort*)w;                                          // 12.8 MB
    unsigned* stag2 = (unsigned*)HA;
    int*      pcnt2 = (int*)(stag2 + (size_t)NBKT * nsb * CAP2);
    int*      pcnt  = pcnt2 + NBKT * nsb;
    int*      sbase = pcnt + NBKT;
    float*    out   = (float*)d_out;

    const int T  = 256;
    const int NB = (N + T - 1) / T;  // 391

    // ---- CSR build (coalesced-write counting sort) + norm ---------------------
    zero_i32_kernel<<<(NBKT * nsb + NBKT + T - 1) / T, T, 0, stream>>>(pcnt2, NBKT * nsb + NBKT);
    bin_kernel<<<1024, T, 0, stream>>>(row, col, pcnt, stag1, E, span);
    bin2_kernel<<<8 * (CAP / 4096), T, 0, stream>>>(stag1, pcnt, pcnt2, stag2, nsb);
    scan_small_kernel<<<1, 1024, 0, stream>>>(pcnt2, sbase, NBKT * nsb);
    sort_sub_kernel<<<8 * nsb, T, 0, stream>>>(stag2, pcnt2, sbase, offs2, eidx, span, nsb, E);
    dinv2_kernel<<<NB, T, 0, stream>>>(offs2, dinv, N);

    const int g64 = (N + 63) / 64;
    const int f64 = (N + 63) / 64;     // fused F_OUT=64: 64 rows/block
    const int f32b = (N + 127) / 128;  // fused F_OUT=32: 128 rows/block
    const int a32 = (N * 4 + T - 1) / T;

    // ---- layer 1: H1 = (x @ W1)*dinv -------------------------------------------
    gemm_tile_kernel<128, 64, false><<<g64, T, 0, stream>>>(x, W1, dinv, HA, N);
    // ---- layer 2 (agg1 + gemm2 fused) ------------------------------------------
    fused_agg_gemm_kernel<64><<<f64, T, 0, stream>>>(HA, offs2, eidx, dinv, b1, W2, HB, N);
    // ---- layer 3 (agg2 + gemm3 fused) ------------------------------------------
    fused_agg_gemm_kernel<64><<<f64, T, 0, stream>>>(HB, offs2, eidx, dinv, b2, W3, HA, N);
    // ---- layer 4 gemm (agg3 + gemm4 fused, F_OUT=32) ---------------------------
    fused_agg_gemm_kernel<32><<<f32b, T, 0, stream>>>(HA, offs2, eidx, dinv, b3, W4, HB, N);
    // ---- layer 4 agg -> d_out ---------------------------------------------------
    agg_half_kernel<32><<<a32, T, 0, stream>>>(HB, offs2, eidx, dinv, b4, out, N);
}

// Round 15
// 295.691 us; speedup vs baseline: 1.4359x; 1.0195x over previous
//
#include <hip/hip_runtime.h>
#include <hip/hip_fp16.h>

// ---------------------------------------------------------------------------
// GCN forward. CSR build = 3-level radix/counting sort (coalesced writes).
// Layers fused (agg_prev + gemm). Round-15 change: LDS input tile in fp16 ->
// 25.6 KB LDS/block -> 6 blocks/CU (round-14: 43 KB -> 3 blocks -> 20% occ
// starved the TLP-hidden gather phase).
//   gemm1: H1 = (x @ W1) * dinv
//   fused2/3/4: relu(b_prev + dinv*aggH) @ W * dinv -> H'   (fp16 ping-pong)
//   agg32 : b4 + dinv*aggH4 -> d_out (f32)
// ---------------------------------------------------------------------------

#define NBKT 8
#define CAP  262144   // per-partition staging cap (E/8 = 200k avg)
#define SUBD 128      // dests per sub-bin
#define CAP2 4096     // per-sub-bin cap (mean 2048, sigma ~45)

__global__ __launch_bounds__(256) void zero_i32_kernel(int* __restrict__ p, int n) {
    int i = blockIdx.x * blockDim.x + threadIdx.x;
    if (i < n) p[i] = 0;
}

// Pass 1: bin edges by dest partition. LDS count -> block bulk-reserve ->
// append packed (r<<14 | c-lo) to stag1[part]. Append-contiguous writes.
__global__ __launch_bounds__(256) void bin_kernel(const int* __restrict__ row,
                                                  const int* __restrict__ col,
                                                  int* __restrict__ pcnt,
                                                  unsigned* __restrict__ stag,
                                                  int E, int span) {
    __shared__ int scnt[NBKT];
    __shared__ int gbase[NBKT];
    const int tid = threadIdx.x;
    for (int base = blockIdx.x * 1024; base < E; base += gridDim.x * 1024) {
        if (tid < NBKT) scnt[tid] = 0;
        __syncthreads();
        int e0 = base + tid * 4;
        unsigned pk[4]; int pt[4], lp[4];
        if (e0 + 4 <= E) {
            int4 r4 = *(const int4*)(row + e0);
            int4 c4 = *(const int4*)(col + e0);
            int rr[4] = {r4.x, r4.y, r4.z, r4.w};
            int cc[4] = {c4.x, c4.y, c4.z, c4.w};
#pragma unroll
            for (int u = 0; u < 4; ++u) {
                int p = cc[u] / span;
                pt[u] = p;
                pk[u] = ((unsigned)rr[u] << 14) | (unsigned)(cc[u] - p * span);
                lp[u] = atomicAdd(&scnt[p], 1);
            }
        } else {
#pragma unroll
            for (int u = 0; u < 4; ++u) {
                int e = e0 + u;
                if (e < E) {
                    int r = row[e], c = col[e];
                    int p = c / span;
                    pt[u] = p;
                    pk[u] = ((unsigned)r << 14) | (unsigned)(c - p * span);
                    lp[u] = atomicAdd(&scnt[p], 1);
                } else pt[u] = -1;
            }
        }
        __syncthreads();
        if (tid < NBKT) gbase[tid] = atomicAdd(&pcnt[tid], scnt[tid]);
        __syncthreads();
#pragma unroll
        for (int u = 0; u < 4; ++u) {
            if (e0 + u < E) {
                stag[(size_t)pt[u] * CAP + (unsigned)(gbase[pt[u]] + lp[u])] = pk[u];
            }
        }
        __syncthreads();
    }
}

// Pass 2: within partition, bin by sub-bin (c_local>>7). Repack (r<<7 | c&127).
__global__ __launch_bounds__(256) void bin2_kernel(const unsigned* __restrict__ stag1,
                                                   const int* __restrict__ pcnt,
                                                   int* __restrict__ pcnt2,
                                                   unsigned* __restrict__ stag2,
                                                   int nsb) {
    __shared__ int scnt[128];
    __shared__ int gbase[128];
    const int part = blockIdx.x & 7;
    const int n = min(pcnt[part], CAP);
    const unsigned* s = stag1 + (size_t)part * CAP;
    const int t0 = (blockIdx.x >> 3) * 4096;
    if (t0 >= n) return;
    const int tn = min(4096, n - t0);
    const int tid = threadIdx.x;

    for (int i = tid; i < nsb; i += 256) scnt[i] = 0;
    __syncthreads();
    for (int i = tid; i < tn; i += 256) {
        unsigned v = s[t0 + i];
        atomicAdd(&scnt[(v & 0x3FFF) >> 7], 1);
    }
    __syncthreads();
    for (int i = tid; i < nsb; i += 256) {
        gbase[i] = atomicAdd(&pcnt2[part * nsb + i], scnt[i]);
        scnt[i] = 0;
    }
    __syncthreads();
    for (int i = tid; i < tn; i += 256) {
        unsigned v = s[t0 + i];
        int cl = v & 0x3FFF;
        int sb = cl >> 7;
        int lp = atomicAdd(&scnt[sb], 1);
        int pos = min(gbase[sb] + lp, CAP2 - 1);  // clamp (never triggers)
        stag2[(size_t)(part * nsb + sb) * CAP2 + pos] = ((v >> 14) << 7) | (unsigned)(cl & 127);
    }
}

// exclusive scan of src[n] -> dst[n], n <= 1024, single block
__global__ __launch_bounds__(1024) void scan_small_kernel(const int* __restrict__ src,
                                                          int* __restrict__ dst, int n) {
    __shared__ int s[1024];
    int tid = threadIdx.x;
    int v = (tid < n) ? src[tid] : 0;
    s[tid] = v;
    __syncthreads();
    for (int off = 1; off < 1024; off <<= 1) {
        int t = (tid >= off) ? s[tid - off] : 0;
        __syncthreads();
        s[tid] += t;
        __syncthreads();
    }
    if (tid < n) dst[tid] = s[tid] - v;
}

// Pass 3: one workgroup per sub-bin. LDS counting sort over 1024 keys
// (c_local7 * 8 + src_bucket); writes offs2 segment + sorted eidx coalesced.
__global__ __launch_bounds__(256) void sort_sub_kernel(const unsigned* __restrict__ stag2,
                                                       const int* __restrict__ pcnt2,
                                                       const int* __restrict__ sbase,
                                                       int* __restrict__ offs2,
                                                       int* __restrict__ eidx,
                                                       int span, int nsb, int E) {
    __shared__ int cnt[1024];
    __shared__ int tsum[256];
    __shared__ int lout[CAP2];
    const int part = blockIdx.x & 7;
    const int sb   = blockIdx.x >> 3;
    if (sb >= nsb) return;
    const int sbg  = part * nsb + sb;
    const int n    = min(pcnt2[sbg], CAP2);
    const unsigned* s = stag2 + (size_t)sbg * CAP2;
    const int base = sbase[sbg];
    const int c0   = part * span + sb * SUBD;
    const int dd   = min(SUBD, span - sb * SUBD);
    const int tid  = threadIdx.x;

    for (int i = tid; i < 1024; i += 256) cnt[i] = 0;
    __syncthreads();
    for (int i = tid; i < n; i += 256) {
        unsigned v = s[i];
        int r = v >> 7;
        atomicAdd(&cnt[((v & 127) << 3) | (r / span)], 1);
    }
    __syncthreads();
    int a0 = cnt[tid * 4], a1 = cnt[tid * 4 + 1], a2 = cnt[tid * 4 + 2], a3 = cnt[tid * 4 + 3];
    int tot = a0 + a1 + a2 + a3;
    tsum[tid] = tot;
    __syncthreads();
    for (int off = 1; off < 256; off <<= 1) {
        int t = (tid >= off) ? tsum[tid - off] : 0;
        __syncthreads();
        tsum[tid] += t;
        __syncthreads();
    }
    int pre = tsum[tid] - tot;
    cnt[tid * 4]     = pre;
    cnt[tid * 4 + 1] = pre + a0;
    cnt[tid * 4 + 2] = pre + a0 + a1;
    cnt[tid * 4 + 3] = pre + a0 + a1 + a2;
    __syncthreads();
    for (int k = tid; k < dd * 8; k += 256) offs2[(size_t)c0 * 8 + k] = base + cnt[k];
    if (part == NBKT - 1 && sb == nsb - 1 && tid == 0) offs2[(size_t)(c0 + dd) * 8] = base + n;
    __syncthreads();
    for (int i = tid; i < n; i += 256) {
        unsigned v = s[i];
        int r = v >> 7;
        int p = atomicAdd(&cnt[((v & 127) << 3) | (r / span)], 1);
        lout[p] = r;
    }
    __syncthreads();
    for (int i = tid; i < n; i += 256) eidx[base + i] = lout[i];
}

__global__ __launch_bounds__(256) void dinv2_kernel(const int* __restrict__ offs2,
                                                    float* __restrict__ dinv, int N) {
    int i = blockIdx.x * blockDim.x + threadIdx.x;
    if (i < N) {
        int deg = offs2[i * NBKT + NBKT] - offs2[i * NBKT];
        dinv[i] = rsqrtf((float)deg + 1.0f);  // +1 self-loop
    }
}

// H(fp16) = ((RELU? relu(in) : in) @ W) * dinv[row].  W is [F_IN,F_OUT] rowmaj.
// Used only for layer 1 (x f32 input).
template <int F_IN, int F_OUT, bool RELU>
__global__ __launch_bounds__(256, 4) void gemm_tile_kernel(const float* __restrict__ in,
                                                           const float* __restrict__ W,
                                                           const float* __restrict__ dinv,
                                                           ushort* __restrict__ outh, int N) {
    constexpr int TC   = F_OUT / 4;
    constexpr int TR   = 256 / TC;
    constexpr int ROWS = TR * 4;
    constexpr int NKB  = F_IN / 64;
    __shared__ float sIn[ROWS][68];
    __shared__ float sW[64][F_OUT];

    const int tc = threadIdx.x % TC;
    const int tr = threadIdx.x / TC;
    const int r0 = blockIdx.x * ROWS;

    float acc[4][4] = {};

#pragma unroll
    for (int kb = 0; kb < NKB; ++kb) {
        if (kb) __syncthreads();
        for (int idx = threadIdx.x; idx < ROWS * 16; idx += 256) {
            int rr = idx / 16, c4 = (idx % 16) * 4;
            int gr = min(r0 + rr, N - 1);
            float4 v = *(const float4*)&in[(size_t)gr * F_IN + kb * 64 + c4];
            if (RELU) {
                v.x = fmaxf(v.x, 0.f); v.y = fmaxf(v.y, 0.f);
                v.z = fmaxf(v.z, 0.f); v.w = fmaxf(v.w, 0.f);
            }
            *(float4*)&sIn[rr][c4] = v;
        }
        for (int idx = threadIdx.x; idx < 64 * F_OUT / 4; idx += 256) {
            int kr = idx / (F_OUT / 4), c4 = (idx % (F_OUT / 4)) * 4;
            *(float4*)&sW[kr][c4] = *(const float4*)&W[(size_t)(kb * 64 + kr) * F_OUT + c4];
        }
        __syncthreads();
#pragma unroll 2
        for (int kk = 0; kk < 64; kk += 4) {
            float4 iv[4], wv[4];
#pragma unroll
            for (int i = 0; i < 4; ++i) iv[i] = *(const float4*)&sIn[tr * 4 + i][kk];
#pragma unroll
            for (int q = 0; q < 4; ++q) wv[q] = *(const float4*)&sW[kk + q][tc * 4];
#pragma unroll
            for (int i = 0; i < 4; ++i) {
                const float ik[4] = {iv[i].x, iv[i].y, iv[i].z, iv[i].w};
#pragma unroll
                for (int q = 0; q < 4; ++q) {
                    acc[i][0] = fmaf(ik[q], wv[q].x, acc[i][0]);
                    acc[i][1] = fmaf(ik[q], wv[q].y, acc[i][1]);
                    acc[i][2] = fmaf(ik[q], wv[q].z, acc[i][2]);
                    acc[i][3] = fmaf(ik[q], wv[q].w, acc[i][3]);
                }
            }
        }
    }
#pragma unroll
    for (int i = 0; i < 4; ++i) {
        int r = r0 + tr * 4 + i;
        if (r < N) {
            float d = dinv[r];
            ushort4 v;
            v.x = __half_as_ushort(__float2half(acc[i][0] * d));
            v.y = __half_as_ushort(__float2half(acc[i][1] * d));
            v.z = __half_as_ushort(__float2half(acc[i][2] * d));
            v.w = __half_as_ushort(__float2half(acc[i][3] * d));
            *(ushort4*)&outh[(size_t)r * F_OUT + tc * 4] = v;
        }
    }
}

__device__ inline void h8acc(float* acc, uint4 u) {
    const __half2* p = (const __half2*)&u;
#pragma unroll
    for (int i = 0; i < 4; ++i) {
        float2 f = __half22float2(p[i]);
        acc[2 * i]     += f.x;
        acc[2 * i + 1] += f.y;
    }
}

// Fused layer: block owns ROWS dest nodes. Phase 1: aggregate each node's
// neighbors from hin, apply bias_prev + dinv + ReLU, write fp16 row to LDS
// (one uint4 per lane; stride 72 ushorts = 144 B keeps 16 B alignment).
// Phase 2: register-tiled GEMM reading fp16 LDS.
template <int F_OUT>
__global__ __launch_bounds__(256, 6) void fused_agg_gemm_kernel(
    const ushort* __restrict__ hin,      // N x 64 fp16 (pre-scaled by dinv[src])
    const int* __restrict__ offs2,
    const int* __restrict__ eidx,
    const float* __restrict__ dinv,
    const float* __restrict__ bias,      // bias of the PREVIOUS conv (64)
    const float* __restrict__ W,         // 64 x F_OUT
    ushort* __restrict__ hout, int N) {
    constexpr int TC   = F_OUT / 4;      // 16 or 8
    constexpr int TR   = 256 / TC;       // 16 or 32
    constexpr int ROWS = TR * 4;         // 64 or 128
    constexpr int L    = 8;              // uint4s per 64-wide fp16 row
    __shared__ ushort sIn[ROWS][72];     // fp16 tile: 9.2/18.4 KB
    __shared__ float  sW[64][F_OUT];     // 16.4/8.2 KB

    const int tid = threadIdx.x;
    const int r0  = blockIdx.x * ROWS;
    const uint4* hv = (const uint4*)hin;

    // ---- phase 1: aggregate ROWS nodes, 32 nodes per pass --------------------
    const int jw  = tid & 7;
    const int grp = tid >> 3;            // 0..31
    float bj[8];
#pragma unroll
    for (int i = 0; i < 8; ++i) bj[i] = bias[jw * 8 + i];

#pragma unroll
    for (int pass = 0; pass < ROWS / 32; ++pass) {
        int rl  = pass * 32 + grp;
        int seg = r0 + rl;
        uint4 pack;
        if (seg < N) {
            float a0[8] = {}, a1[8] = {};
            int k = offs2[(size_t)seg * NBKT];
            const int e = offs2[(size_t)seg * NBKT + NBKT];
            for (; k + 4 <= e; k += 4) {
                int s0 = eidx[k], s1 = eidx[k + 1], s2 = eidx[k + 2], s3 = eidx[k + 3];
                uint4 u0 = hv[(size_t)s0 * L + jw];
                uint4 u1 = hv[(size_t)s1 * L + jw];
                uint4 u2 = hv[(size_t)s2 * L + jw];
                uint4 u3 = hv[(size_t)s3 * L + jw];
                h8acc(a0, u0); h8acc(a1, u1); h8acc(a0, u2); h8acc(a1, u3);
            }
            if (k + 2 <= e) {
                int s0 = eidx[k], s1 = eidx[k + 1];
                uint4 u0 = hv[(size_t)s0 * L + jw];
                uint4 u1 = hv[(size_t)s1 * L + jw];
                h8acc(a0, u0); h8acc(a1, u1);
                k += 2;
            }
            if (k < e) h8acc(a0, hv[(size_t)eidx[k] * L + jw]);
            h8acc(a0, hv[(size_t)seg * L + jw]);  // self-loop
            float d = dinv[seg];
            __half2* ph = (__half2*)&pack;
#pragma unroll
            for (int i = 0; i < 4; ++i) {
                float v0 = fmaxf(bj[2 * i]     + d * (a0[2 * i]     + a1[2 * i]),     0.0f);
                float v1 = fmaxf(bj[2 * i + 1] + d * (a0[2 * i + 1] + a1[2 * i + 1]), 0.0f);
                ph[i] = __floats2half2_rn(v0, v1);
            }
        } else {
            pack = make_uint4(0, 0, 0, 0);
        }
        *(uint4*)&sIn[rl][jw * 8] = pack;
    }
    // ---- stage W --------------------------------------------------------------
    for (int idx = tid; idx < 64 * F_OUT / 4; idx += 256) {
        int kr = idx / (F_OUT / 4), c4 = (idx % (F_OUT / 4)) * 4;
        *(float4*)&sW[kr][c4] = *(const float4*)&W[(size_t)kr * F_OUT + c4];
    }
    __syncthreads();

    // ---- phase 2: GEMM (fp16 LDS reads, f32 math) -----------------------------
    const int tc = tid % TC;
    const int tr = tid / TC;
    float acc[4][4] = {};
#pragma unroll 2
    for (int kk = 0; kk < 64; kk += 4) {
        float4 wv[4];
#pragma unroll
        for (int q = 0; q < 4; ++q) wv[q] = *(const float4*)&sW[kk + q][tc * 4];
#pragma unroll
        for (int i = 0; i < 4; ++i) {
            uint2 u = *(const uint2*)&sIn[tr * 4 + i][kk];
            const __half2* ph = (const __half2*)&u;
            float2 f0 = __half22float2(ph[0]);
            float2 f1 = __half22float2(ph[1]);
            const float ik[4] = {f0.x, f0.y, f1.x, f1.y};
#pragma unroll
            for (int q = 0; q < 4; ++q) {
                acc[i][0] = fmaf(ik[q], wv[q].x, acc[i][0]);
                acc[i][1] = fmaf(ik[q], wv[q].y, acc[i][1]);
                acc[i][2] = fmaf(ik[q], wv[q].z, acc[i][2]);
                acc[i][3] = fmaf(ik[q], wv[q].w, acc[i][3]);
            }
        }
    }
#pragma unroll
    for (int i = 0; i < 4; ++i) {
        int r = r0 + tr * 4 + i;
        if (r < N) {
            float d = dinv[r];
            ushort4 v;
            v.x = __half_as_ushort(__float2half(acc[i][0] * d));
            v.y = __half_as_ushort(__float2half(acc[i][1] * d));
            v.z = __half_as_ushort(__float2half(acc[i][2] * d));
            v.w = __half_as_ushort(__float2half(acc[i][3] * d));
            *(ushort4*)&hout[(size_t)r * F_OUT + tc * 4] = v;
        }
    }
}

// Final: out[c] = b + dinv[c]*( sum_{neighbors} H16[r] + H16[c] ), f32 out.
template <int F>
__global__ __launch_bounds__(256) void agg_half_kernel(const ushort* __restrict__ h,
                                                       const int* __restrict__ offs2,
                                                       const int* __restrict__ eidx,
                                                       const float* __restrict__ dinv,
                                                       const float* __restrict__ b,
                                                       float* __restrict__ out, int N) {
    constexpr int L = F / 8;
    int tid = blockIdx.x * 256 + threadIdx.x;
    int seg = tid / L;
    int jw  = tid % L;
    if (seg >= N) return;
    const uint4* hv = (const uint4*)h;

    int k = offs2[(size_t)seg * NBKT];
    const int e = offs2[(size_t)seg * NBKT + NBKT];

    float a0[8] = {}, a1[8] = {};
    for (; k + 4 <= e; k += 4) {
        int r0 = eidx[k], r1 = eidx[k + 1], r2 = eidx[k + 2], r3 = eidx[k + 3];
        uint4 u0 = hv[(size_t)r0 * L + jw];
        uint4 u1 = hv[(size_t)r1 * L + jw];
        uint4 u2 = hv[(size_t)r2 * L + jw];
        uint4 u3 = hv[(size_t)r3 * L + jw];
        h8acc(a0, u0); h8acc(a1, u1); h8acc(a0, u2); h8acc(a1, u3);
    }
    if (k + 2 <= e) {
        int r0 = eidx[k], r1 = eidx[k + 1];
        uint4 u0 = hv[(size_t)r0 * L + jw];
        uint4 u1 = hv[(size_t)r1 * L + jw];
        h8acc(a0, u0); h8acc(a1, u1);
        k += 2;
    }
    if (k < e) h8acc(a0, hv[(size_t)eidx[k] * L + jw]);

    h8acc(a0, hv[(size_t)seg * L + jw]);  // self-loop
#pragma unroll
    for (int i = 0; i < 8; ++i) a0[i] += a1[i];

    float  d  = dinv[seg];
    float4 b0 = *(const float4*)&b[jw * 8];
    float4 b1 = *(const float4*)&b[jw * 8 + 4];
    float4 o0 = {b0.x + d * a0[0], b0.y + d * a0[1], b0.z + d * a0[2], b0.w + d * a0[3]};
    float4 o1 = {b1.x + d * a0[4], b1.y + d * a0[5], b1.z + d * a0[6], b1.w + d * a0[7]};
    *(float4*)&out[(size_t)seg * F + jw * 8]     = o0;
    *(float4*)&out[(size_t)seg * F + jw * 8 + 4] = o1;
}

extern "C" void kernel_launch(void* const* d_in, const int* in_sizes, int n_in,
                              void* d_out, int out_size, void* d_ws, size_t ws_size,
                              hipStream_t stream) {
    const float* x  = (const float*)d_in[0];
    const int*   ei = (const int*)d_in[1];
    const float* W1 = (const float*)d_in[2];
    const float* b1 = (const float*)d_in[3];
    const float* W2 = (const float*)d_in[4];
    const float* b2 = (const float*)d_in[5];
    const float* W3 = (const float*)d_in[6];
    const float* b3 = (const float*)d_in[7];
    const float* W4 = (const float*)d_in[8];
    const float* b4 = (const float*)d_in[9];

    const int N = in_sizes[0] / 128;  // 100000
    const int E = in_sizes[1] / 2;    // 1600000
    const int* row = ei;              // source
    const int* col = ei + E;          // destination
    const int n2   = N * NBKT;
    const int span = (N + NBKT - 1) / NBKT;   // 12500
    const int nsb  = (span + SUBD - 1) / SUBD; // 98

    // ---- workspace layout ----------------------------------------------------
    // persistent: offs2, dinv, eidx, stag1, HA, HB (fp16 ping-pong)
    // transient:  stag2/pcnt2/pcnt/sbase alias HA+HB (dead before gemm1/fused2)
    char* w = (char*)d_ws;
    int*      offs2 = (int*)w;               w += (size_t)(n2 + 4) * 4;
    float*    dinv  = (float*)w;             w += (size_t)N * 4;
    int*      eidx  = (int*)w;               w += (size_t)E * 4;
    unsigned* stag1 = (unsigned*)w;          w += (size_t)NBKT * CAP * 4;  // 8.4 MB
    ushort*   HA    = (ushort*)w;            w += (size_t)N * 64 * 2;      // 12.8 MB
    ushort*   HB    = (ushort*)w;                                          // 12.8 MB
    unsigned* stag2 = (unsigned*)HA;
    int*      pcnt2 = (int*)(stag2 + (size_t)NBKT * nsb * CAP2);
    int*      pcnt  = pcnt2 + NBKT * nsb;
    int*      sbase = pcnt + NBKT;
    float*    out   = (float*)d_out;

    const int T  = 256;
    const int NB = (N + T - 1) / T;  // 391

    // ---- CSR build (coalesced-write counting sort) + norm ---------------------
    zero_i32_kernel<<<(NBKT * nsb + NBKT + T - 1) / T, T, 0, stream>>>(pcnt2, NBKT * nsb + NBKT);
    bin_kernel<<<1024, T, 0, stream>>>(row, col, pcnt, stag1, E, span);
    bin2_kernel<<<8 * (CAP / 4096), T, 0, stream>>>(stag1, pcnt, pcnt2, stag2, nsb);
    scan_small_kernel<<<1, 1024, 0, stream>>>(pcnt2, sbase, NBKT * nsb);
    sort_sub_kernel<<<8 * nsb, T, 0, stream>>>(stag2, pcnt2, sbase, offs2, eidx, span, nsb, E);
    dinv2_kernel<<<NB, T, 0, stream>>>(offs2, dinv, N);

    const int g64 = (N + 63) / 64;
    const int f64 = (N + 63) / 64;     // fused F_OUT=64: 64 rows/block
    const int f32b = (N + 127) / 128;  // fused F_OUT=32: 128 rows/block
    const int a32 = (N * 4 + T - 1) / T;

    // ---- layer 1: H1 = (x @ W1)*dinv -------------------------------------------
    gemm_tile_kernel<128, 64, false><<<g64, T, 0, stream>>>(x, W1, dinv, HA, N);
    // ---- layer 2 (agg1 + gemm2 fused) ------------------------------------------
    fused_agg_gemm_kernel<64><<<f64, T, 0, stream>>>(HA, offs2, eidx, dinv, b1, W2, HB, N);
    // ---- layer 3 (agg2 + gemm3 fused) ------------------------------------------
    fused_agg_gemm_kernel<64><<<f64, T, 0, stream>>>(HB, offs2, eidx, dinv, b2, W3, HA, N);
    // ---- layer 4 gemm (agg3 + gemm4 fused, F_OUT=32) ---------------------------
    fused_agg_gemm_kernel<32><<<f32b, T, 0, stream>>>(HA, offs2, eidx, dinv, b3, W4, HB, N);
    // ---- layer 4 agg -> d_out ---------------------------------------------------
    agg_half_kernel<32><<<a32, T, 0, stream>>>(HB, offs2, eidx, dinv, b4, out, N);
}